// Round 1
// baseline (311.044 us; speedup 1.0000x reference)
//
#include <hip/hip_runtime.h>
#include <hip/hip_bf16.h>
#include <stdint.h>

// Problem constants (from reference): N=8, T=200, U=50, E=D=J=512, V=500.
#define M_TOTAL 80000   // N*T*U
#define JD 512
#define VV 500

typedef short short8 __attribute__((ext_vector_type(8)));
typedef float floatx4 __attribute__((ext_vector_type(4)));

__device__ inline short f2bf(float f) {
    // RNE fp32 -> bf16 (values are finite; no NaN handling needed)
    uint32_t u = __float_as_uint(f);
    uint32_t r = (u + 0x7FFFu + ((u >> 16) & 1u)) >> 16;
    return (short)r;
}

__device__ inline float fast_tanh(float x) {
    // tanh(x) = 1 - 2/(exp(2x)+1); v_exp_f32 is exp2 natively.
    float e = __builtin_amdgcn_exp2f(x * 2.8853900817779268f); // 2*log2(e)
    return 1.0f - 2.0f * __builtin_amdgcn_rcpf(e + 1.0f);
}

// ---------------------------------------------------------------------------
// Kernel 1: convert inputs/weights to bf16; pad W_out to 512x512 (zero rows).
// ---------------------------------------------------------------------------
__global__ __launch_bounds__(256) void prep_kernel(
    const float* __restrict__ enc, const float* __restrict__ dec,
    const float* __restrict__ Wenc, const float* __restrict__ Wdec,
    const float* __restrict__ Wout,
    short* __restrict__ enc_bf, short* __restrict__ dec_bf,
    short* __restrict__ Wenc_bf, short* __restrict__ Wdec_bf,
    short* __restrict__ Wb)
{
    int i = blockIdx.x * 256 + threadIdx.x;
    const int S0 = 819200, S1 = 204800, S2 = 262144, S3 = 262144, S4 = 262144;
    if (i < S0) { enc_bf[i] = f2bf(enc[i]); return; }
    i -= S0;
    if (i < S1) { dec_bf[i] = f2bf(dec[i]); return; }
    i -= S1;
    if (i < S2) { Wenc_bf[i] = f2bf(Wenc[i]); return; }
    i -= S2;
    if (i < S3) { Wdec_bf[i] = f2bf(Wdec[i]); return; }
    i -= S3;
    if (i < S4) {
        int row = i >> 9, col = i & 511;
        Wb[i] = (row < VV) ? f2bf(Wout[row * JD + col]) : (short)0;
    }
}

// ---------------------------------------------------------------------------
// Kernel 2: projection GEMMs. C[m][j] = sum_e A_bf[m][e]*W_bf[j][e] + bias[j].
// 128x128 tile, BK=64, mfma_f32_16x16x32_bf16, ds_write staging (needs row
// guards for ragged M). Handles enc (M=1600, 13 m-tiles) and dec (M=400, 4).
// ---------------------------------------------------------------------------
__global__ __launch_bounds__(256) void proj_gemm(
    const short* __restrict__ enc_bf, const short* __restrict__ dec_bf,
    const short* __restrict__ Wenc_bf, const short* __restrict__ Wdec_bf,
    const float* __restrict__ b_enc, const float* __restrict__ b_dec,
    float* __restrict__ enc_p, float* __restrict__ dec_p)
{
    __shared__ short As[128 * 64];
    __shared__ short Bs[128 * 64];
    int bx = blockIdx.x, by = blockIdx.y;
    const short* A; const short* W; const float* bias; float* C; int M;
    if (bx < 13) { A = enc_bf; W = Wenc_bf; bias = b_enc; C = enc_p; M = 1600; }
    else { bx -= 13; A = dec_bf; W = Wdec_bf; bias = b_dec; C = dec_p; M = 400; }

    int tid = threadIdx.x;
    int lane = tid & 63, wv = tid >> 6;
    int wm = wv >> 1, wn = wv & 1;
    int l16 = lane & 15, q4 = lane >> 4;

    int r = tid >> 1, h = tid & 1;      // staging: thread covers row r, k-half h
    int m_st = bx * 128 + r;
    bool valid = m_st < M;

    floatx4 acc[4][4];
    #pragma unroll
    for (int a = 0; a < 4; a++)
        #pragma unroll
        for (int b = 0; b < 4; b++) acc[a][b] = (floatx4){0.f, 0.f, 0.f, 0.f};

    for (int kk = 0; kk < 8; kk++) {
        int k0 = kk * 64;
        __syncthreads();
        {
            uint4 z = make_uint4(0, 0, 0, 0);
            uint4 v0 = z, v1 = z, v2 = z, v3 = z;
            if (valid) {
                const uint4* p = (const uint4*)(A + (size_t)m_st * JD + k0 + h * 32);
                v0 = p[0]; v1 = p[1]; v2 = p[2]; v3 = p[3];
            }
            uint4* d = (uint4*)&As[r * 64 + h * 32];
            d[0] = v0; d[1] = v1; d[2] = v2; d[3] = v3;
            const uint4* pb = (const uint4*)(W + (size_t)(by * 128 + r) * JD + k0 + h * 32);
            uint4* db = (uint4*)&Bs[r * 64 + h * 32];
            db[0] = pb[0]; db[1] = pb[1]; db[2] = pb[2]; db[3] = pb[3];
        }
        __syncthreads();
        #pragma unroll
        for (int h2 = 0; h2 < 2; h2++) {
            short8 af[4], bf[4];
            #pragma unroll
            for (int im = 0; im < 4; im++)
                af[im] = *(const short8*)&As[(wm * 64 + im * 16 + l16) * 64 + h2 * 32 + q4 * 8];
            #pragma unroll
            for (int in = 0; in < 4; in++)
                bf[in] = *(const short8*)&Bs[(wn * 64 + in * 16 + l16) * 64 + h2 * 32 + q4 * 8];
            #pragma unroll
            for (int im = 0; im < 4; im++)
                #pragma unroll
                for (int in = 0; in < 4; in++)
                    acc[im][in] = __builtin_amdgcn_mfma_f32_16x16x32_bf16(
                        af[im], bf[in], acc[im][in], 0, 0, 0);
        }
    }
    // epilogue: C/D layout col=lane&15, row=quad*4+reg (measured m89/m91)
    #pragma unroll
    for (int im = 0; im < 4; im++) {
        int mb = bx * 128 + wm * 64 + im * 16 + q4 * 4;
        #pragma unroll
        for (int rr = 0; rr < 4; rr++) {
            int m = mb + rr;
            if (m < M) {
                #pragma unroll
                for (int in = 0; in < 4; in++) {
                    int j = by * 128 + wn * 64 + in * 16 + l16;
                    C[(size_t)m * JD + j] = acc[im][in][rr] + bias[j];
                }
            }
        }
    }
}

// ---------------------------------------------------------------------------
// Kernel 3: act_bf[m][j] = bf16(tanh(enc_p[m/50][j] + dec_p[(m/10000)*50 + m%50][j]))
// One thread per 8 j's; coalesced 16B stores.
// ---------------------------------------------------------------------------
__global__ __launch_bounds__(256) void act_kernel(
    const float* __restrict__ enc_p, const float* __restrict__ dec_p,
    short* __restrict__ act)
{
    int idx = blockIdx.x * 256 + threadIdx.x;   // 80000*64 threads
    int m = idx >> 6;
    int j8 = (idx & 63) << 3;
    int er = m / 50;
    int n  = m / 10000;
    int u  = m - er * 50;
    const float* ep = enc_p + (size_t)er * JD + j8;
    const float* dp = dec_p + (size_t)(n * 50 + u) * JD + j8;
    float4 e0 = *(const float4*)ep, e1 = *(const float4*)(ep + 4);
    float4 d0 = *(const float4*)dp, d1 = *(const float4*)(dp + 4);
    short8 o;
    o[0] = f2bf(fast_tanh(e0.x + d0.x));
    o[1] = f2bf(fast_tanh(e0.y + d0.y));
    o[2] = f2bf(fast_tanh(e0.z + d0.z));
    o[3] = f2bf(fast_tanh(e0.w + d0.w));
    o[4] = f2bf(fast_tanh(e1.x + d1.x));
    o[5] = f2bf(fast_tanh(e1.y + d1.y));
    o[6] = f2bf(fast_tanh(e1.z + d1.z));
    o[7] = f2bf(fast_tanh(e1.w + d1.w));
    *(short8*)(act + (size_t)m * JD + j8) = o;
}

// ---------------------------------------------------------------------------
// Kernel 4: main GEMM. out[m][v] = sum_j act[m][j]*Wb[v][j] + b_out[v].
// m97 recipe: 128x128 tile, BK=64, global_load_lds width-16 staging for A and
// B, linear LDS rows [r][64k] (b128 frag reads are bank-balanced), 4 waves in
// 2x2, each 4x4 of 16x16x32 MFMAs. 625x4 grid; 625*128 = 80000 exactly.
// ---------------------------------------------------------------------------
__global__ __launch_bounds__(256) void joiner_gemm(
    const short* __restrict__ act, const short* __restrict__ Wb,
    const float* __restrict__ b_out, float* __restrict__ out)
{
    __shared__ short As[128 * 64];
    __shared__ short Bs[128 * 64];
    int tid = threadIdx.x;
    int lane = tid & 63, wv = tid >> 6;
    int wm = wv >> 1, wn = wv & 1;
    int l16 = lane & 15, q4 = lane >> 4;
    int bx = blockIdx.x, by = blockIdx.y;

    int srow = lane >> 3;     // row within 8-row staging segment
    int schunk = lane & 7;    // 16B chunk within 128B row

    floatx4 acc[4][4];
    #pragma unroll
    for (int a = 0; a < 4; a++)
        #pragma unroll
        for (int b = 0; b < 4; b++) acc[a][b] = (floatx4){0.f, 0.f, 0.f, 0.f};

    const short* gA = act + (size_t)(bx * 128) * JD;
    const short* gB = Wb + (size_t)(by * 128) * JD;

    for (int kk = 0; kk < 8; kk++) {
        int k0 = kk * 64;
        __syncthreads();
        #pragma unroll
        for (int i = 0; i < 4; i++) {
            int rbase = wv * 32 + i * 8;  // wave-uniform
            const short* ga = gA + (size_t)(rbase + srow) * JD + k0 + schunk * 8;
            __builtin_amdgcn_global_load_lds(
                (const __attribute__((address_space(1))) uint32_t*)ga,
                (__attribute__((address_space(3))) uint32_t*)&As[rbase * 64], 16, 0, 0);
            const short* gb = gB + (size_t)(rbase + srow) * JD + k0 + schunk * 8;
            __builtin_amdgcn_global_load_lds(
                (const __attribute__((address_space(1))) uint32_t*)gb,
                (__attribute__((address_space(3))) uint32_t*)&Bs[rbase * 64], 16, 0, 0);
        }
        __syncthreads();
        #pragma unroll
        for (int h2 = 0; h2 < 2; h2++) {
            short8 af[4], bf[4];
            #pragma unroll
            for (int im = 0; im < 4; im++)
                af[im] = *(const short8*)&As[(wm * 64 + im * 16 + l16) * 64 + h2 * 32 + q4 * 8];
            #pragma unroll
            for (int in = 0; in < 4; in++)
                bf[in] = *(const short8*)&Bs[(wn * 64 + in * 16 + l16) * 64 + h2 * 32 + q4 * 8];
            #pragma unroll
            for (int im = 0; im < 4; im++)
                #pragma unroll
                for (int in = 0; in < 4; in++)
                    acc[im][in] = __builtin_amdgcn_mfma_f32_16x16x32_bf16(
                        af[im], bf[in], acc[im][in], 0, 0, 0);
        }
    }
    // epilogue: m < 80000 always; guard v < 500 only
    #pragma unroll
    for (int im = 0; im < 4; im++) {
        int mb = bx * 128 + wm * 64 + im * 16 + q4 * 4;
        #pragma unroll
        for (int rr = 0; rr < 4; rr++) {
            size_t orow = (size_t)(mb + rr) * VV;
            #pragma unroll
            for (int in = 0; in < 4; in++) {
                int v = by * 128 + wn * 64 + in * 16 + l16;
                if (v < VV) out[orow + v] = acc[im][in][rr] + b_out[v];
            }
        }
    }
}

// ---------------------------------------------------------------------------
extern "C" void kernel_launch(void* const* d_in, const int* in_sizes, int n_in,
                              void* d_out, int out_size, void* d_ws, size_t ws_size,
                              hipStream_t stream)
{
    const float* enc   = (const float*)d_in[0];
    const float* dec   = (const float*)d_in[1];
    const float* Wenc  = (const float*)d_in[2];
    const float* b_enc = (const float*)d_in[3];
    const float* Wdec  = (const float*)d_in[4];
    const float* b_dec = (const float*)d_in[5];
    const float* Wout  = (const float*)d_in[6];
    const float* b_out = (const float*)d_in[7];
    float* out = (float*)d_out;

    // ws layout (bytes): total ~89.6 MB
    char* ws = (char*)d_ws;
    short* Wb      = (short*)(ws + 0);          //  512*512 bf16      = 524288
    short* enc_bf  = (short*)(ws + 524288);     // 1600*512 bf16      = 1638400
    short* dec_bf  = (short*)(ws + 2162688);    //  400*512 bf16      = 409600
    short* Wenc_bf = (short*)(ws + 2572288);    //  512*512 bf16      = 524288
    short* Wdec_bf = (short*)(ws + 3096576);    //  512*512 bf16      = 524288
    float* enc_p   = (float*)(ws + 3620864);    // 1600*512 f32       = 3276800
    float* dec_p   = (float*)(ws + 6897664);    //  400*512 f32       = 819200
    short* act     = (short*)(ws + 7716864);    // 80000*512 bf16     = 81920000

    prep_kernel<<<7072, 256, 0, stream>>>(enc, dec, Wenc, Wdec, Wout,
                                          enc_bf, dec_bf, Wenc_bf, Wdec_bf, Wb);
    proj_gemm<<<dim3(17, 4), 256, 0, stream>>>(enc_bf, dec_bf, Wenc_bf, Wdec_bf,
                                               b_enc, b_dec, enc_p, dec_p);
    act_kernel<<<20000, 256, 0, stream>>>(enc_p, dec_p, act);
    joiner_gemm<<<dim3(625, 4), 256, 0, stream>>>(act, Wb, b_out, out);
}

// Round 2
// 295.733 us; speedup vs baseline: 1.0518x; 1.0518x over previous
//
#include <hip/hip_runtime.h>
#include <hip/hip_bf16.h>
#include <stdint.h>

// Problem constants: N=8, T=200, U=50, E=D=J=512, V=500. M = N*T*U = 80000.
#define JD 512
#define VV 500

typedef short short8 __attribute__((ext_vector_type(8)));
typedef short short4v __attribute__((ext_vector_type(4)));
typedef float floatx4 __attribute__((ext_vector_type(4)));

__device__ inline short f2bf(float f) {
    uint32_t u = __float_as_uint(f);
    uint32_t r = (u + 0x7FFFu + ((u >> 16) & 1u)) >> 16;
    return (short)r;
}

__device__ inline float fast_tanh(float x) {
    // tanh(x) = 1 - 2/(exp(2x)+1); v_exp_f32 is exp2 natively.
    float e = __builtin_amdgcn_exp2f(x * 2.8853900817779268f); // 2*log2(e)
    return 1.0f - 2.0f * __builtin_amdgcn_rcpf(e + 1.0f);
}

// ---------------------------------------------------------------------------
// Kernel 1: fp32 -> bf16 casts; pad W_out to 512x512 (zero rows 500..511).
// ---------------------------------------------------------------------------
__global__ __launch_bounds__(256) void prep_kernel(
    const float* __restrict__ enc, const float* __restrict__ dec,
    const float* __restrict__ Wenc, const float* __restrict__ Wdec,
    const float* __restrict__ Wout,
    short* __restrict__ enc_bf, short* __restrict__ dec_bf,
    short* __restrict__ Wenc_bf, short* __restrict__ Wdec_bf,
    short* __restrict__ Wb)
{
    int i = blockIdx.x * 256 + threadIdx.x;
    const int S0 = 819200, S1 = 204800, S2 = 262144, S3 = 262144, S4 = 262144;
    if (i < S0) { enc_bf[i] = f2bf(enc[i]); return; }
    i -= S0;
    if (i < S1) { dec_bf[i] = f2bf(dec[i]); return; }
    i -= S1;
    if (i < S2) { Wenc_bf[i] = f2bf(Wenc[i]); return; }
    i -= S2;
    if (i < S3) { Wdec_bf[i] = f2bf(Wdec[i]); return; }
    i -= S3;
    if (i < S4) {
        int row = i >> 9, col = i & 511;
        Wb[i] = (row < VV) ? f2bf(Wout[row * JD + col]) : (short)0;
    }
}

// ---------------------------------------------------------------------------
// Kernel 2: projection GEMMs (enc: 1600x512x512, dec: 400x512x512).
// LDS row stride padded 64 -> 72 shorts (144 B = 36 words, +4 banks/row) so
// b128 frag reads hit the 8-phase minimum instead of 16-way conflicts.
// ---------------------------------------------------------------------------
#define PST 72
__global__ __launch_bounds__(256) void proj_gemm(
    const short* __restrict__ enc_bf, const short* __restrict__ dec_bf,
    const short* __restrict__ Wenc_bf, const short* __restrict__ Wdec_bf,
    const float* __restrict__ b_enc, const float* __restrict__ b_dec,
    float* __restrict__ enc_p, float* __restrict__ dec_p)
{
    __shared__ short As[128 * PST];
    __shared__ short Bs[128 * PST];
    int bx = blockIdx.x, by = blockIdx.y;
    const short* A; const short* W; const float* bias; float* C; int M;
    if (bx < 13) { A = enc_bf; W = Wenc_bf; bias = b_enc; C = enc_p; M = 1600; }
    else { bx -= 13; A = dec_bf; W = Wdec_bf; bias = b_dec; C = dec_p; M = 400; }

    int tid = threadIdx.x;
    int lane = tid & 63, wv = tid >> 6;
    int wm = wv >> 1, wn = wv & 1;
    int l16 = lane & 15, q4 = lane >> 4;

    int r = tid >> 1, h = tid & 1;
    int m_st = bx * 128 + r;
    bool valid = m_st < M;

    floatx4 acc[4][4];
    #pragma unroll
    for (int a = 0; a < 4; a++)
        #pragma unroll
        for (int b = 0; b < 4; b++) acc[a][b] = (floatx4){0.f, 0.f, 0.f, 0.f};

    for (int kk = 0; kk < 8; kk++) {
        int k0 = kk * 64;
        __syncthreads();
        {
            uint4 z = make_uint4(0, 0, 0, 0);
            uint4 v0 = z, v1 = z, v2 = z, v3 = z;
            if (valid) {
                const uint4* p = (const uint4*)(A + (size_t)m_st * JD + k0 + h * 32);
                v0 = p[0]; v1 = p[1]; v2 = p[2]; v3 = p[3];
            }
            uint4* d = (uint4*)&As[r * PST + h * 32];
            d[0] = v0; d[1] = v1; d[2] = v2; d[3] = v3;
            const uint4* pb = (const uint4*)(W + (size_t)(by * 128 + r) * JD + k0 + h * 32);
            uint4* db = (uint4*)&Bs[r * PST + h * 32];
            db[0] = pb[0]; db[1] = pb[1]; db[2] = pb[2]; db[3] = pb[3];
        }
        __syncthreads();
        #pragma unroll
        for (int h2 = 0; h2 < 2; h2++) {
            short8 af[4], bf[4];
            #pragma unroll
            for (int im = 0; im < 4; im++)
                af[im] = *(const short8*)&As[(wm * 64 + im * 16 + l16) * PST + h2 * 32 + q4 * 8];
            #pragma unroll
            for (int in = 0; in < 4; in++)
                bf[in] = *(const short8*)&Bs[(wn * 64 + in * 16 + l16) * PST + h2 * 32 + q4 * 8];
            #pragma unroll
            for (int im = 0; im < 4; im++)
                #pragma unroll
                for (int in = 0; in < 4; in++)
                    acc[im][in] = __builtin_amdgcn_mfma_f32_16x16x32_bf16(
                        af[im], bf[in], acc[im][in], 0, 0, 0);
        }
    }
    #pragma unroll
    for (int im = 0; im < 4; im++) {
        int mb = bx * 128 + wm * 64 + im * 16 + q4 * 4;
        #pragma unroll
        for (int rr = 0; rr < 4; rr++) {
            int m = mb + rr;
            if (m < M) {
                #pragma unroll
                for (int in = 0; in < 4; in++) {
                    int j = by * 128 + wn * 64 + in * 16 + l16;
                    C[(size_t)m * JD + j] = acc[im][in][rr] + bias[j];
                }
            }
        }
    }
}

// ---------------------------------------------------------------------------
// Kernel 3: FUSED act + vocab GEMM.
// Grid 625 x 512 threads. Per block:
//  Phase 1: compute act tile (128 m-rows x 512 j) = tanh(enc_p+dec_p) as bf16
//           directly into LDS (act never touches HBM). Row stride 520 shorts
//           (1040 B = 260 words -> +4 banks/row): frag-read bank for lane
//           (l16,q4) = (l16+q4)*4 -> exactly the 8-phase b128 minimum.
//  Phase 2: out[128 x 512] = act x Wb^T over K=512. A-frags from LDS, B-frags
//           loaded straight from L2-resident Wb (512 KB), double-buffered in
//           registers; 32 MFMAs (~600 cyc) cover the ~200 cyc L2 latency.
//  8 waves as 2x4: wave tile 64x128, acc = 4x8 x floatx4 = 128 VGPRs.
// ---------------------------------------------------------------------------
#define AST 520
__global__ __launch_bounds__(512, 2) void fused_joiner(
    const float* __restrict__ enc_p, const float* __restrict__ dec_p,
    const short* __restrict__ Wb, const float* __restrict__ b_out,
    float* __restrict__ out)
{
    __shared__ short As[128 * AST];   // 133,120 B (gfx950 LDS = 160 KiB)
    int tid = threadIdx.x;
    int bx = blockIdx.x;

    // ---- Phase 1: act tile -> LDS
    {
        int rsub = tid >> 7;            // 0..3 rows per pass
        int jf = (tid & 127) * 4;       // fp32 j offset, coalesced per row
        #pragma unroll 4
        for (int pass = 0; pass < 32; pass++) {
            int row = pass * 4 + rsub;
            int m = bx * 128 + row;
            int er = m / 50;            // n*200 + t
            int n  = m / 10000;
            int dr = n * 50 + (m - er * 50);
            float4 e = *(const float4*)(enc_p + (size_t)er * JD + jf);
            float4 d = *(const float4*)(dec_p + (size_t)dr * JD + jf);
            short4v o;
            o[0] = f2bf(fast_tanh(e.x + d.x));
            o[1] = f2bf(fast_tanh(e.y + d.y));
            o[2] = f2bf(fast_tanh(e.z + d.z));
            o[3] = f2bf(fast_tanh(e.w + d.w));
            *(short4v*)&As[row * AST + jf] = o;
        }
    }
    __syncthreads();

    // ---- Phase 2: GEMM
    int lane = tid & 63, wv = tid >> 6;
    int wm = wv >> 2, wn = wv & 3;      // 2 x 4 wave grid
    int l16 = lane & 15, q4 = lane >> 4;

    floatx4 acc[4][8];
    #pragma unroll
    for (int a = 0; a < 4; a++)
        #pragma unroll
        for (int b = 0; b < 8; b++) acc[a][b] = (floatx4){0.f, 0.f, 0.f, 0.f};

    int abase[4];
    #pragma unroll
    for (int im = 0; im < 4; im++)
        abase[im] = (wm * 64 + im * 16 + l16) * AST + q4 * 8;
    int boff[8];
    #pragma unroll
    for (int in = 0; in < 8; in++)
        boff[in] = (wn * 128 + in * 16 + l16) * JD + q4 * 8;

    // B double-buffer: preload ks=0
    short8 b0[8], b1[8];
    #pragma unroll
    for (int in = 0; in < 8; in++)
        b0[in] = *(const short8*)(Wb + boff[in]);

    for (int ks = 0; ks < 16; ks += 2) {
        int k1 = (ks + 1) * 32;
        #pragma unroll
        for (int in = 0; in < 8; in++)
            b1[in] = *(const short8*)(Wb + boff[in] + k1);
        {
            int k0 = ks * 32;
            short8 af[4];
            #pragma unroll
            for (int im = 0; im < 4; im++)
                af[im] = *(const short8*)&As[abase[im] + k0];
            #pragma unroll
            for (int im = 0; im < 4; im++)
                #pragma unroll
                for (int in = 0; in < 8; in++)
                    acc[im][in] = __builtin_amdgcn_mfma_f32_16x16x32_bf16(
                        af[im], b0[in], acc[im][in], 0, 0, 0);
        }
        if (ks + 2 < 16) {
            int k2 = (ks + 2) * 32;
            #pragma unroll
            for (int in = 0; in < 8; in++)
                b0[in] = *(const short8*)(Wb + boff[in] + k2);
        }
        {
            short8 af[4];
            #pragma unroll
            for (int im = 0; im < 4; im++)
                af[im] = *(const short8*)&As[abase[im] + k1];
            #pragma unroll
            for (int im = 0; im < 4; im++)
                #pragma unroll
                for (int in = 0; in < 8; in++)
                    acc[im][in] = __builtin_amdgcn_mfma_f32_16x16x32_bf16(
                        af[im], b1[in], acc[im][in], 0, 0, 0);
        }
    }

    // ---- Epilogue: bias + store (m always < 80000; guard v < 500)
    float bo[8];
    #pragma unroll
    for (int in = 0; in < 8; in++) {
        int v = wn * 128 + in * 16 + l16;
        bo[in] = (v < VV) ? b_out[v] : 0.f;
    }
    #pragma unroll
    for (int im = 0; im < 4; im++) {
        int mb = bx * 128 + wm * 64 + im * 16 + q4 * 4;
        #pragma unroll
        for (int rr = 0; rr < 4; rr++) {
            size_t orow = (size_t)(mb + rr) * VV;
            #pragma unroll
            for (int in = 0; in < 8; in++) {
                int v = wn * 128 + in * 16 + l16;
                if (v < VV) out[orow + v] = acc[im][in][rr] + bo[in];
            }
        }
    }
}

// ---------------------------------------------------------------------------
extern "C" void kernel_launch(void* const* d_in, const int* in_sizes, int n_in,
                              void* d_out, int out_size, void* d_ws, size_t ws_size,
                              hipStream_t stream)
{
    const float* enc   = (const float*)d_in[0];
    const float* dec   = (const float*)d_in[1];
    const float* Wenc  = (const float*)d_in[2];
    const float* b_enc = (const float*)d_in[3];
    const float* Wdec  = (const float*)d_in[4];
    const float* b_dec = (const float*)d_in[5];
    const float* Wout  = (const float*)d_in[6];
    const float* b_out = (const float*)d_in[7];
    float* out = (float*)d_out;

    // ws layout (bytes): ~7.7 MB total
    char* ws = (char*)d_ws;
    short* Wb      = (short*)(ws + 0);          //  512*512 bf16
    short* enc_bf  = (short*)(ws + 524288);     // 1600*512 bf16
    short* dec_bf  = (short*)(ws + 2162688);    //  400*512 bf16
    short* Wenc_bf = (short*)(ws + 2572288);    //  512*512 bf16
    short* Wdec_bf = (short*)(ws + 3096576);    //  512*512 bf16
    float* enc_p   = (float*)(ws + 3620864);    // 1600*512 f32
    float* dec_p   = (float*)(ws + 6897664);    //  400*512 f32

    prep_kernel<<<7072, 256, 0, stream>>>(enc, dec, Wenc, Wdec, Wout,
                                          enc_bf, dec_bf, Wenc_bf, Wdec_bf, Wb);
    proj_gemm<<<dim3(17, 4), 256, 0, stream>>>(enc_bf, dec_bf, Wenc_bf, Wdec_bf,
                                               b_enc, b_dec, enc_p, dec_p);
    fused_joiner<<<625, 512, 0, stream>>>(enc_p, dec_p, Wb, b_out, out);
}